// Round 10
// baseline (295.515 us; speedup 1.0000x reference)
//
#include <hip/hip_runtime.h>
#include <math.h>

// ---------------- Workspace layout (bytes) ----------------
// QT bf16  @ 0         : 4194304   [8][8][1024][32]  (scale folded)
// KT bf16  @ 4194304   : 4194304   [8][8][1024][32]
// VT bf16  @ 8388608   : 4194304   [8][256][1024]
// feats f32@ 0         : 33554432  [4][8][256][1024] RAW conv sums; planes 1,2,3
//                                  zeroed in gemm_oproj's tail (after flash_attn —
//                                  they alias KT/VT) and atomically accumulated;
//                                  plane 0 (k1) plain-stored.
// S    f32 @ 41943040  : 8192      (cross-block: agent-scope atomics only)
// bar  u32 @ 41951232  : 4         (tail grid barrier; zeroed by gemm_oproj)
// P1 bf16  @ 41984000  : 5914624   [8][38][38][256]  (x-padded, later oproj-out;
//                                  border zeroed once in prep_all)
// P2 bf16  @ 47898624  : 5914624   [8][38][38][256]  (attn-out; border never read)
// Wq bf16  @ 53813248  : 393216
// Wo bf16  @ 54206464  : 131072
// Wc bf16  @ 54337536  : 10944512  (k1,k3,k5,k7)
// binv f32 @ 65347584  : 4096
// bb2  f32 @ 65351680  : 4096
// total ~65.4 MB
//
// LEDGER (structural results, do not re-attempt):
//  - conv 2-barrier LDS-staged tap loop = 848 TF eff (~92% of structure ceiling).
//    R2 counted-vmcnt: null. R7 register-direct A (barrier-free): -90% (L1/L2
//    traffic 4x, thrashes 32KB L1). LDS A-staging is load-bearing.
//  - R4 per-cs atomic flush: WRITE_SIZE 3x -> 2.2x slower. Current chunking is
//    the balance-vs-writeback optimum.
//  - R9 cg::grid.sync()+plain S stores: absmax 0.55. Cross-block data MUST use
//    agent-scope atomics; barrier hand-rolled (co-residency by launch_bounds).

typedef __attribute__((ext_vector_type(8))) short bf16x8;
typedef __attribute__((ext_vector_type(4))) float f32x4;

__device__ __forceinline__ ushort f2bf(float f) {
  uint32_t u = __float_as_uint(f);
  u += 0x7fffu + ((u >> 16) & 1u);
  return (ushort)(u >> 16);
}

__device__ __forceinline__ uint cvt_pk(float lo, float hi) {
  uint r;
  asm volatile("v_cvt_pk_bf16_f32 %0, %1, %2" : "=v"(r) : "v"(lo), "v"(hi));
  return r;
}

// ---- merged preprocessing: repacks + pad_cvt + bn_fold + P1 border zero ----

template <int KK>
__device__ __forceinline__ void repack_dev(const float* __restrict__ src,
                                           ushort* __restrict__ dst, int M, int co,
                                           char* smraw) {
  if constexpr (KK == 1) {  // identity layout: plain f32->bf16 cast, no LDS
    int tid = threadIdx.x;
    dst[(size_t)co * 256 + tid] = f2bf(src[(size_t)co * 256 + tid]);
    return;
  } else {
    ushort(*t)[KK + 1] = (ushort(*)[KK + 1])smraw;
    int tid = threadIdx.x;
    for (int idx = tid; idx < 256 * KK; idx += 256) {
      int ci = idx / KK, k = idx - ci * KK;
      t[ci][k] = f2bf(src[(size_t)co * 256 * KK + idx]);
    }
    __syncthreads();
    for (int idx = tid; idx < 256 * KK; idx += 256) {
      int k = idx >> 8, ci = idx & 255;
      dst[((size_t)k * M + co) * 256 + ci] = t[ci][k];
    }
  }
}

__device__ __forceinline__ void pad_dev(const float* __restrict__ src,
                                        ushort* __restrict__ dst, int y, int b,
                                        char* smraw) {
  ushort(*t)[258] = (ushort(*)[258])smraw;
  int tid = threadIdx.x;
  for (int u = 0; u < 32; ++u) {
    int idx = u * 256 + tid;
    int c = idx >> 5, p = idx & 31;
    t[p][c] = f2bf(src[(((size_t)b * 256 + c) << 10) + (y << 5) + p]);
  }
  __syncthreads();
  for (int u = 0; u < 32; ++u) {
    int idx = u * 256 + tid;
    int p = idx >> 8, c = idx & 255;
    dst[(((size_t)b * 38 + y + 3) * 38 + p + 3) * 256 + c] = t[p][c];
  }
}

__global__ __launch_bounds__(256) void prep_all(
    const float* __restrict__ qkv_w, const float* __restrict__ out_w,
    const float* __restrict__ cw1, const float* __restrict__ cw3,
    const float* __restrict__ cw5, const float* __restrict__ cw7,
    ushort* __restrict__ Wq, ushort* __restrict__ Wo, ushort* __restrict__ Wc,
    const float* __restrict__ x, ushort* __restrict__ P1,
    const float* __restrict__ cb, const float* __restrict__ g,
    const float* __restrict__ be, const float* __restrict__ mn,
    const float* __restrict__ v, float* __restrict__ binv, float* __restrict__ bb2) {
  __shared__ __align__(16) char sm[25600];
  int gx = blockIdx.x;
  if (gx < 768) repack_dev<1>(qkv_w, Wq, 768, gx, sm);
  else if (gx < 1024) repack_dev<1>(out_w, Wo, 256, gx - 768, sm);
  else if (gx < 1280) repack_dev<1>(cw1, Wc, 256, gx - 1024, sm);
  else if (gx < 1536) repack_dev<9>(cw3, Wc + 65536, 256, gx - 1280, sm);
  else if (gx < 1792) repack_dev<25>(cw5, Wc + 655360, 256, gx - 1536, sm);
  else if (gx < 2048) repack_dev<49>(cw7, Wc + 2293760, 256, gx - 1792, sm);
  else if (gx < 2304) pad_dev(x, P1, (gx - 2048) & 31, (gx - 2048) >> 5, sm);
  else if (gx == 2304) {
    int tid = threadIdx.x;
#pragma unroll
    for (int u = 0; u < 4; ++u) {
      int i = u * 256 + tid;
      float inv = g[i] * rsqrtf(v[i] + 1e-5f);
      binv[i] = inv;
      bb2[i] = be[i] + (cb[i] - mn[i]) * inv;
    }
  } else {  // gx in [2305, 2369): zero P1 padded border (420 px x 256 ch per b)
    int z = gx - 2305;     // 0..63
    int b = z >> 3;        // 0..7
    int part = z & 7;      // 8 parts x 1680 uint4
    uint4* b4 = (uint4*)(P1 + (size_t)b * 369664);
    uint4 z4; z4.x = z4.y = z4.z = z4.w = 0u;
    for (int q = 0; q < 7; ++q) {
      int idx = q * 256 + threadIdx.x;
      if (idx < 1680) {
        int uidx = part * 1680 + idx;
        int p = uidx >> 5, ch = uidx & 31;
        int y, xx;
        if (p < 114) { y = p / 38; xx = p - y * 38; }
        else if (p < 306) {
          int r = p - 114; int ry = r / 6; int xi = r - ry * 6;
          y = 3 + ry; xx = xi < 3 ? xi : xi + 32;
        } else {
          int r = p - 306; int ry = r / 38; y = 35 + ry; xx = r - ry * 38;
        }
        b4[(y * 38 + xx) * 32 + ch] = z4;
      }
    }
  }
}

// ---- core: implicit-im2col MFMA conv/GEMM.
// MODE 0: qkv split -> QT/KT/VT bf16; MODE 1: padded bf16 out;
// MODE 2: raw f32 out (plain store or atomic accumulate for K-split chunks)
// Per-tap sync: {issue A-prefetch; vmcnt(2); barrier; ds_read+MFMA; raw barrier}.
template <int MODE>
__device__ __forceinline__ void conv_core(
    const ushort* __restrict__ W, const ushort* __restrict__ X,
    float* __restrict__ outF, ushort* __restrict__ outU,
    int M, int KS, int b, int co0, int pxt, int cs0, int cs1, bool accum,
    char* smem) {
  const int R = KS >> 1;
  const int NT = KS * KS;
  const int NR = 4 + 2 * R;
  const int NPIX = NR * 38;
  char* Bs = smem;
  char* As = smem + 24320;
  const int tid = threadIdx.x;
  const int w = tid >> 6, l = tid & 63, lr = l & 15, sg = l >> 4;
  const int y0 = pxt * 4;
  const ushort* Xb = X + ((size_t)b * 38 + (y0 + 3 - R)) * 38 * 256;

  f32x4 acc[4][4] = {};

  auto stageA = [&](int t, int ci0, int bufsel) {
    const ushort* Wt = W + ((size_t)t * M + co0) * 256 + ci0;
    char* dbase = As + (bufsel << 13) + (w << 11);
#pragma unroll
    for (int u = 0; u < 2; ++u) {
      int idx16 = (w * 2 + u) * 64 + l;
      int co = idx16 >> 2, s = idx16 & 3;
      const ushort* src = Wt + (size_t)co * 256 + ((s ^ ((co >> 1) & 3)) << 3);
      __builtin_amdgcn_global_load_lds(
          (const __attribute__((address_space(1))) void*)src,
          (__attribute__((address_space(3))) void*)(dbase + (u << 10)), 16, 0, 0);
    }
  };

  int g = 0;
  stageA(0, cs0 << 5, 0);
  const int u_stg = (NPIX * 4 + 255) >> 8;
  for (int cs = cs0; cs < cs1; ++cs) {
    int ci0 = cs << 5;
    for (int u = 0; u < u_stg; ++u) {
      int idx = (u << 8) + tid;
      if (idx < NPIX * 4) {
        int pix = idx >> 2, s = idx & 3;
        int pr = pix / 38, pc = pix - pr * 38;
        const ushort* srcp = Xb + ((size_t)(pr * 38 + pc)) * 256 + ci0 +
                             ((s ^ ((pc >> 1) & 3)) << 3);
        __builtin_amdgcn_global_load_lds(
            (const __attribute__((address_space(1))) void*)srcp,
            (__attribute__((address_space(3))) void*)(Bs + (u << 12) + (w << 10)),
            16, 0, 0);
      }
    }
    __syncthreads();  // full drain: B tile + pending A prefetch must land
    int dy = 0, dx = 0;
    for (int t = 0; t < NT; ++t) {
      bool staged = true;
      if (t + 1 < NT) stageA(t + 1, ci0, (g + 1) & 1);
      else if (cs + 1 < cs1) stageA(0, ci0 + 32, (g + 1) & 1);
      else staged = false;
      if (staged)
        asm volatile("s_waitcnt vmcnt(2)\n\ts_barrier" ::: "memory");
      else
        asm volatile("s_waitcnt vmcnt(0)\n\ts_barrier" ::: "memory");

      bf16x8 af[4], bfr[4];
      char* Ab = As + ((g & 1) << 13);
#pragma unroll
      for (int fa = 0; fa < 4; ++fa) {
        int co = (w & 1) * 64 + fa * 16 + lr;
        af[fa] = *(const bf16x8*)(Ab + (co << 6) + ((sg ^ ((co >> 1) & 3)) << 4));
      }
      int rowbase = (w >> 1) * 2 + dy;
      int cbase = dx + 3 - R + lr;
#pragma unroll
      for (int fp = 0; fp < 4; ++fp) {
        int lrow = rowbase + (fp >> 1);
        int pc = cbase + ((fp & 1) << 4);
        bfr[fp] = *(const bf16x8*)(Bs + ((lrow * 38 + pc) << 6) +
                                   ((sg ^ ((pc >> 1) & 3)) << 4));
      }
      __builtin_amdgcn_s_setprio(1);
#pragma unroll
      for (int fa = 0; fa < 4; ++fa)
#pragma unroll
        for (int fp = 0; fp < 4; ++fp)
          acc[fa][fp] = __builtin_amdgcn_mfma_f32_16x16x32_bf16(
              af[fa], bfr[fp], acc[fa][fp], 0, 0, 0);
      __builtin_amdgcn_s_setprio(0);
      ++g;
      if (++dx == KS) { dx = 0; ++dy; }
      asm volatile("s_barrier" ::: "memory");
    }
  }
  // epilogue
  int coB = co0 + (w & 1) * 64;
  int pxB = pxt * 128 + (w >> 1) * 64;
#pragma unroll
  for (int fa = 0; fa < 4; ++fa) {
#pragma unroll
    for (int fp = 0; fp < 4; ++fp) {
      int px = pxB + (fp >> 1) * 32 + (fp & 1) * 16 + lr;
      int cobase = coB + fa * 16 + 4 * sg;
      f32x4 v4 = acc[fa][fp];
      if (MODE == 2) {
#pragma unroll
        for (int r = 0; r < 4; ++r) {
          int co = cobase + r;
          float* dst = &outF[((size_t)b * M + co) * 1024 + px];
          if (accum) unsafeAtomicAdd(dst, v4[r]);
          else *dst = v4[r];
        }
      } else if (MODE == 1) {
        int y = px >> 5, x = px & 31;
        ushort* dst = outU + ((size_t)(b * 38 + y + 3) * 38 + x + 3) * 256 + cobase;
        *(uint*)dst = cvt_pk(v4[0], v4[1]);
        *(uint*)(dst + 2) = cvt_pk(v4[2], v4[3]);
      } else {  // MODE 0: split into QT / KT / VT
        if (coB < 256) {
          int h = cobase >> 5, d = cobase & 31;
          ushort* dst = outU + ((size_t)(b * 8 + h) * 1024 + px) * 32 + d;
          const float sc = 0.17677669529663687f;
          *(uint*)dst = cvt_pk(v4[0] * sc, v4[1] * sc);
          *(uint*)(dst + 2) = cvt_pk(v4[2] * sc, v4[3] * sc);
        } else if (coB < 512) {
          int c2 = cobase - 256;
          int h = c2 >> 5, d = c2 & 31;
          ushort* dst = outU + 2097152 + ((size_t)(b * 8 + h) * 1024 + px) * 32 + d;
          *(uint*)dst = cvt_pk(v4[0], v4[1]);
          *(uint*)(dst + 2) = cvt_pk(v4[2], v4[3]);
        } else {
          int c2 = cobase - 512;
#pragma unroll
          for (int r = 0; r < 4; ++r)
            outU[4194304 + ((size_t)(b * 256 + c2 + r)) * 1024 + px] = f2bf(v4[r]);
        }
      }
    }
  }
}

__global__ __launch_bounds__(256, 2) void gemm_qkv(const ushort* __restrict__ W,
                                                   const ushort* __restrict__ X,
                                                   ushort* __restrict__ U) {
  __shared__ __align__(16) char smem[40704];
  int cot = blockIdx.x >> 3, pxt = blockIdx.x & 7, b = blockIdx.y;
  conv_core<0>(W, X, nullptr, U, 768, 1, b, cot * 128, pxt, 0, 8, false, smem);
}

// oproj + feats-plane zeroing tail (replaces the 25 MB memset dispatch) + bar=0.
// Planes 1-3 alias KT/VT; legal because oproj runs after flash_attn.
__global__ __launch_bounds__(256, 2) void gemm_oproj(const ushort* __restrict__ W,
                                                     const ushort* __restrict__ X,
                                                     ushort* __restrict__ U,
                                                     float* __restrict__ fz,
                                                     uint* __restrict__ bar) {
  __shared__ __align__(16) char smem[40704];
  int cot = blockIdx.x >> 3, pxt = blockIdx.x & 7, b = blockIdx.y;
  conv_core<1>(W, X, nullptr, U, 256, 1, b, cot * 128, pxt, 0, 8, false, smem);
  // zero 25165824 B across 128 blocks: 196608 B/block = 12288 float4
  int blk = blockIdx.y * 16 + blockIdx.x;
  float4* dst = (float4*)fz + (size_t)blk * 12288;
  float4 z4 = {0.f, 0.f, 0.f, 0.f};
#pragma unroll
  for (int q = 0; q < 48; ++q) dst[q * 256 + threadIdx.x] = z4;
  if (blk == 0 && threadIdx.x == 0)
    __hip_atomic_store(bar, 0u, __ATOMIC_RELAXED, __HIP_MEMORY_SCOPE_AGENT);
}

// 1024 blocks, all co-resident (4 blocks/CU @ 40.75KB LDS, 16 waves/CU).
// K-chunked for balance (tap-units): k7 -> 4 chunks of 2 cs (98, 512 blocks),
// k5 -> 2 chunks of 4 cs (100, 256), k3 -> 2 chunks of 4 cs (36, 256);
// k3-chunk0 blocks additionally run the tiny k1 (8). Per-CU load: 340/332 taps.
__global__ __launch_bounds__(256, 4) void conv_fused(const ushort* __restrict__ Wc,
                                                     const ushort* __restrict__ X,
                                                     float* __restrict__ feats) {
  __shared__ __align__(16) char smem[40704];
  int gx = blockIdx.x;
  int sub = gx & 127;
  int pxt = sub & 7, cot = (sub >> 3) & 1, b = sub >> 4;
  int br, cs0, cs1;
  if (gx < 512) {
    br = 3; int ch = gx >> 7; cs0 = ch * 2; cs1 = cs0 + 2;
  } else if (gx < 768) {
    br = 2; int ch = (gx >> 7) & 1; cs0 = ch * 4; cs1 = cs0 + 4;
  } else {
    br = 1; int ch = (gx >> 7) & 1; cs0 = ch * 4; cs1 = cs0 + 4;
  }
  const int ksarr[4] = {1, 3, 5, 7};
  const int wofs[4] = {0, 65536, 655360, 2293760};
  conv_core<2>(Wc + wofs[br], X, feats + (size_t)br * 2097152, nullptr, 256,
               ksarr[br], b, cot * 128, pxt, cs0, cs1, true, smem);
  if (gx >= 768 && gx < 896) {  // k3-chunk0 blocks also do k1 (plain store)
    __syncthreads();
    conv_core<2>(Wc, X, feats, nullptr, 256, 1, b, cot * 128, pxt, 0, 8, false,
                 smem);
  }
}

// ---- flash attention: QT/KT [bh][1024][32] bf16, VT [b*256+c][1024] bf16.
// Grid (8 qtiles, 64 bh). 4 waves x 32 queries. KV tiles of 64.
// K/V register-direct (L2-resident), 2-deep dbuf, barrier-free.
__global__ __launch_bounds__(256, 2) void flash_attn(const ushort* __restrict__ QKV,
                                                     ushort* __restrict__ P2out) {
  __shared__ __align__(16) char smem[16384];
  const int tid = threadIdx.x, w = tid >> 6, l = tid & 63, lr = l & 15, sg = l >> 4;
  char* Ps = smem + (w << 12);  // per-wave [32 i][8 slots 16B] swizzled
  int bh = blockIdx.y, b = bh >> 3, h = bh & 7;
  const ushort* QT = QKV + (size_t)bh * 32768;
  const ushort* KT = QKV + 2097152 + (size_t)bh * 32768;
  const ushort* VT = QKV + 4194304 + (size_t)(b * 256 + h * 32) * 1024;
  int ibase = blockIdx.x * 128 + w * 32;

  bf16x8 qf[2];
#pragma unroll
  for (int i16 = 0; i16 < 2; ++i16)
    qf[i16] = *(const bf16x8*)(QT + ((size_t)(ibase + i16 * 16 + lr)) * 32 + sg * 8);

  f32x4 oacc[4] = {};  // [d16*2 + i16]
  float mrow[2] = {-3e30f, -3e30f};
  float lrow[2] = {0.f, 0.f};

  const ushort* Krow = KT + (size_t)lr * 32 + sg * 8;
  const ushort* Vrow = VT + (size_t)lr * 1024 + sg * 8;

  bf16x8 k0[4], v0[4], k1[4], v1[4];
  auto LK = [&](int jb, bf16x8* kf) {
#pragma unroll
    for (int jt = 0; jt < 4; ++jt)
      kf[jt] = *(const bf16x8*)(Krow + ((size_t)jb + jt * 16) * 32);
  };
  auto LV = [&](int jb, bf16x8* vf) {
#pragma unroll
    for (int d16 = 0; d16 < 2; ++d16)
#pragma unroll
      for (int h2 = 0; h2 < 2; ++h2)
        vf[d16 * 2 + h2] =
            *(const bf16x8*)(Vrow + (size_t)d16 * 16384 + jb + h2 * 32);
  };

  auto body = [&](int jb, bf16x8* kc, bf16x8* vc, bf16x8* kn, bf16x8* vn) {
    if (jb + 64 < 1024) { LK(jb + 64, kn); LV(jb + 64, vn); }  // prefetch next
    f32x4 sac[2][4] = {};
#pragma unroll
    for (int i16 = 0; i16 < 2; ++i16)
#pragma unroll
      for (int jt = 0; jt < 4; ++jt)
        sac[i16][jt] = __builtin_amdgcn_mfma_f32_16x16x32_bf16(
            kc[jt], qf[i16], sac[i16][jt], 0, 0, 0);

#pragma unroll
    for (int i16 = 0; i16 < 2; ++i16) {
      float tmax = sac[i16][0][0];
#pragma unroll
      for (int jt = 0; jt < 4; ++jt)
#pragma unroll
        for (int r = 0; r < 4; ++r) tmax = fmaxf(tmax, sac[i16][jt][r]);
      tmax = fmaxf(tmax, __shfl_xor(tmax, 16));
      tmax = fmaxf(tmax, __shfl_xor(tmax, 32));
      float mnew = fmaxf(mrow[i16], tmax);
      float fac = __expf(mrow[i16] - mnew);
      mrow[i16] = mnew;
      float psum = 0.f;
      int i = i16 * 16 + lr;
      char* prow = Ps + i * 128;
#pragma unroll
      for (int jt = 0; jt < 4; ++jt) {
        float p0 = __expf(sac[i16][jt][0] - mnew);
        float p1 = __expf(sac[i16][jt][1] - mnew);
        float p2 = __expf(sac[i16][jt][2] - mnew);
        float p3 = __expf(sac[i16][jt][3] - mnew);
        psum += (p0 + p1) + (p2 + p3);
        int j0 = jt * 16 + sg * 4;
        uint* dst = (uint*)(prow + (((j0 >> 3) ^ (i & 7)) << 4) + ((j0 & 7) << 1));
        dst[0] = cvt_pk(p0, p1);
        dst[1] = cvt_pk(p2, p3);
      }
      lrow[i16] = lrow[i16] * fac + psum;
#pragma unroll
      for (int d16 = 0; d16 < 2; ++d16)
#pragma unroll
        for (int r = 0; r < 4; ++r) oacc[d16 * 2 + i16][r] *= fac;
    }
    asm volatile("s_waitcnt lgkmcnt(0)" ::: "memory");

#pragma unroll
    for (int h2 = 0; h2 < 2; ++h2) {
      bf16x8 pf[2];
#pragma unroll
      for (int i16 = 0; i16 < 2; ++i16) {
        int i = i16 * 16 + lr;
        pf[i16] = *(const bf16x8*)(Ps + i * 128 + ((((h2 << 2) + sg) ^ (i & 7)) << 4));
      }
#pragma unroll
      for (int d16 = 0; d16 < 2; ++d16)
#pragma unroll
        for (int i16 = 0; i16 < 2; ++i16)
          oacc[d16 * 2 + i16] = __builtin_amdgcn_mfma_f32_16x16x32_bf16(
              vc[d16 * 2 + h2], pf[i16], oacc[d16 * 2 + i16], 0, 0, 0);
    }
  };

  LK(0, k0);
  LV(0, v0);
#pragma unroll 1
  for (int jb = 0; jb < 1024; jb += 128) {
    body(jb, k0, v0, k1, v1);
    body(jb + 64, k1, v1, k0, v0);
  }

  float linv[2];
#pragma unroll
  for (int i16 = 0; i16 < 2; ++i16) {
    float lt = lrow[i16];
    lt += __shfl_xor(lt, 16);
    lt += __shfl_xor(lt, 32);
    linv[i16] = 1.0f / lt;
  }
#pragma unroll
  for (int i16 = 0; i16 < 2; ++i16) {
    int i = ibase + i16 * 16 + lr;
    int y = i >> 5, x = i & 31;
    ushort* dst0 = P2out + ((size_t)(b * 38 + y + 3) * 38 + x + 3) * 256 + h * 32 + sg * 4;
#pragma unroll
    for (int d16 = 0; d16 < 2; ++d16) {
      f32x4 v = oacc[d16 * 2 + i16];
      ushort* dst = dst0 + d16 * 16;
      *(uint*)dst = cvt_pk(v[0] * linv[i16], v[1] * linv[i16]);
      *(uint*)(dst + 2) = cvt_pk(v[2] * linv[i16], v[3] * linv[i16]);
    }
  }
}

// ---- fused tail: reduce_s + fc/softmax + combine in ONE regular kernel.
// 1024 blocks x 256 threads, __launch_bounds__(256,4) (VGPR<=128, LDS 2.2KB)
// -> exactly 4 blocks/CU capacity => all 1024 co-resident => hand-rolled
// arrive-and-wait barrier is safe (bounded spin as a hang-guard).
// Cross-block data (S) uses AGENT-SCOPE atomics only (R9 lesson: plain stores
// are not visible across non-coherent per-XCD L2s).
__global__ __launch_bounds__(256, 4) void fused_tail(
    const float* __restrict__ feats, const float* __restrict__ binv,
    const float* __restrict__ bb2, const float* __restrict__ fc_w,
    const float* __restrict__ fc_b, const float* __restrict__ fcs_w,
    const float* __restrict__ fcs_b, float* __restrict__ S,
    uint* __restrict__ bar, float* __restrict__ out) {
  __shared__ float red[256];
  __shared__ float Ss[256];
  __shared__ float Zs[32];
  const int tid = threadIdx.x;
  const int bc0 = blockIdx.x * 2;
  float4 ya[4], yb[4];

  // ---- phase 1: BN+ReLU into regs, reduce S per bc (agent-scope store)
#pragma unroll
  for (int half = 0; half < 2; ++half) {
    int bc = bc0 + half;
    int c = bc & 255;
    const float4* p4 = (const float4*)feats + (size_t)bc * 256;
    float s = 0.f;
    float4* y = half ? yb : ya;
#pragma unroll
    for (int k = 0; k < 4; ++k) {
      float bi = binv[k * 256 + c], bo = bb2[k * 256 + c];
      float4 v = p4[(size_t)k * 524288 + tid];
      float4 r;
      r.x = fmaxf(fmaf(v.x, bi, bo), 0.f);
      r.y = fmaxf(fmaf(v.y, bi, bo), 0.f);
      r.z = fmaxf(fmaf(v.z, bi, bo), 0.f);
      r.w = fmaxf(fmaf(v.w, bi, bo), 0.f);
      y[k] = r;
      s += (r.x + r.y) + (r.z + r.w);
    }
    red[tid] = s;
    __syncthreads();
    for (int off = 128; off > 0; off >>= 1) {
      if (tid < off) red[tid] += red[tid + off];
      __syncthreads();
    }
    if (tid == 0)
      __hip_atomic_store(&S[bc], red[0] * (1.0f / 1024.0f), __ATOMIC_RELAXED,
                         __HIP_MEMORY_SCOPE_AGENT);
    __syncthreads();
  }

  // ---- grid barrier: arrive-and-wait on agent-scope counter
  __threadfence();
  __syncthreads();
  if (tid == 0) {
    __hip_atomic_fetch_add(bar, 1u, __ATOMIC_ACQ_REL, __HIP_MEMORY_SCOPE_AGENT);
    long guard = 0;
    while (__hip_atomic_load(bar, __ATOMIC_ACQUIRE, __HIP_MEMORY_SCOPE_AGENT) <
               1024u &&
           guard < (1L << 26)) {
      __builtin_amdgcn_s_sleep(8);
      ++guard;
    }
  }
  __syncthreads();

  // ---- phase 2: fc -> attnw -> combine from registers (agent-scope S loads)
  const int b = bc0 >> 8;
  Ss[tid] = __hip_atomic_load(&S[b * 256 + tid], __ATOMIC_RELAXED,
                              __HIP_MEMORY_SCOPE_AGENT);
  __syncthreads();
  if (tid < 32) {
    float z = fc_b[tid];
    const float* wp = &fc_w[tid * 256];
    for (int c = 0; c < 256; ++c) z += Ss[c] * wp[c];
    Zs[tid] = z;
  }
  __syncthreads();

#pragma unroll
  for (int half = 0; half < 2; ++half) {
    int bc = bc0 + half;
    int c = bc & 255;
    const float4* y = half ? yb : ya;
    float lg[4];
#pragma unroll
    for (int k = 0; k < 4; ++k) {
      float v = fcs_b[k * 256 + c];
      const float* wp = &fcs_w[((size_t)k * 256 + c) * 32];
#pragma unroll
      for (int d = 0; d < 32; ++d) v += wp[d] * Zs[d];
      lg[k] = v;
    }
    float m = fmaxf(fmaxf(lg[0], lg[1]), fmaxf(lg[2], lg[3]));
    float e0 = __expf(lg[0] - m), e1 = __expf(lg[1] - m);
    float e2 = __expf(lg[2] - m), e3 = __expf(lg[3] - m);
    float inv = 1.0f / (e0 + e1 + e2 + e3);
    float aw[4] = {e0 * inv, e1 * inv, e2 * inv, e3 * inv};
    float4 o = {0.f, 0.f, 0.f, 0.f};
#pragma unroll
    for (int k = 0; k < 4; ++k) {
      o.x += aw[k] * y[k].x;
      o.y += aw[k] * y[k].y;
      o.z += aw[k] * y[k].z;
      o.w += aw[k] * y[k].w;
    }
    ((float4*)out)[(size_t)bc * 256 + tid] = o;
  }
}

extern "C" void kernel_launch(void* const* d_in, const int* in_sizes, int n_in,
                              void* d_out, int out_size, void* d_ws, size_t ws_size,
                              hipStream_t stream) {
  (void)in_sizes; (void)n_in; (void)out_size; (void)ws_size;
  const float* x      = (const float*)d_in[0];
  const float* qkv_w  = (const float*)d_in[1];
  const float* out_w  = (const float*)d_in[2];
  const float* cw1    = (const float*)d_in[3];
  const float* cw3    = (const float*)d_in[4];
  const float* cw5    = (const float*)d_in[5];
  const float* cw7    = (const float*)d_in[6];
  const float* conv_b = (const float*)d_in[7];
  const float* bn_g   = (const float*)d_in[8];
  const float* bn_b   = (const float*)d_in[9];
  const float* bn_m   = (const float*)d_in[10];
  const float* bn_v   = (const float*)d_in[11];
  const float* fc_w   = (const float*)d_in[12];
  const float* fc_b   = (const float*)d_in[13];
  const float* fcs_w  = (const float*)d_in[14];
  const float* fcs_b  = (const float*)d_in[15];

  char*  wsb   = (char*)d_ws;
  float* wsf   = (float*)d_ws;
  ushort* QKVb = (ushort*)d_ws;             // QT | KT(+2097152) | VT(+4194304)
  float* feats = wsf;                       // overlaps QKV buffers (dead by then)
  float* S     = wsf + 10485760;
  uint*  bar   = (uint*)(wsb + 41951232);
  ushort* P1   = (ushort*)(wsb + 41984000);
  ushort* P2   = (ushort*)(wsb + 47898624);
  ushort* Wq   = (ushort*)(wsb + 53813248);
  ushort* Wo   = (ushort*)(wsb + 54206464);
  ushort* Wc   = (ushort*)(wsb + 54337536);
  float* binv  = (float*)(wsb + 65347584);
  float* bb2   = (float*)(wsb + 65351680);
  float* out   = (float*)d_out;

  prep_all<<<2369, 256, 0, stream>>>(qkv_w, out_w, cw1, cw3, cw5, cw7, Wq, Wo, Wc,
                                     x, P1, conv_b, bn_g, bn_b, bn_m, bn_v,
                                     binv, bb2);

  gemm_qkv<<<dim3(48, 8), 256, 0, stream>>>(Wq, P1, QKVb);
  flash_attn<<<dim3(8, 64), 256, 0, stream>>>(QKVb, P2);
  // gemm_oproj's tail zeroes feats planes 1-3 (alias KT/VT; flash is done) + bar.
  gemm_oproj<<<dim3(16, 8), 256, 0, stream>>>(Wo, P2, P1,
                                              (float*)(wsb + 8388608), bar);
  conv_fused<<<dim3(1024), 256, 0, stream>>>(Wc, P1, feats);

  fused_tail<<<1024, 256, 0, stream>>>(feats, binv, bb2, fc_w, fc_b, fcs_w,
                                       fcs_b, S, bar, out);
}

// Round 11
// 197.611 us; speedup vs baseline: 1.4954x; 1.4954x over previous
//
#include <hip/hip_runtime.h>
#include <math.h>

// ---------------- Workspace layout (bytes) ----------------
// QT bf16  @ 0         : 4194304   [8][8][1024][32]  (scale folded)
// KT bf16  @ 4194304   : 4194304   [8][8][1024][32]
// VT bf16  @ 8388608   : 4194304   [8][256][1024]
// feats f32@ 0         : 33554432  [4][8][256][1024] RAW conv sums; planes 1,2,3
//                                  zeroed in gemm_oproj's tail (after flash_attn —
//                                  they alias KT/VT) and atomically accumulated;
//                                  plane 0 (k1) plain-stored.
// S    f32 @ 41943040  : 8192
// P1 bf16  @ 41984000  : 5914624   [8][38][38][256]  (x-padded, later oproj-out;
//                                  border zeroed once in prep_all)
// P2 bf16  @ 47898624  : 5914624   [8][38][38][256]  (attn-out; border never read)
// Wq bf16  @ 53813248  : 393216
// Wo bf16  @ 54206464  : 131072
// Wc bf16  @ 54337536  : 10944512  (k1,k3,k5,k7)
// binv f32 @ 65347584  : 4096
// bb2  f32 @ 65351680  : 4096
// total ~65.4 MB
//
// LEDGER (structural results, do not re-attempt):
//  - conv 2-barrier LDS-staged tap loop = 848 TF eff (~92% of structure ceiling).
//    R2 counted-vmcnt: null. R7 register-direct A (barrier-free): -90% (L1/L2
//    traffic 4x, thrashes 32KB L1). LDS A-staging is load-bearing.
//  - R4 per-cs atomic flush: WRITE_SIZE 3x -> 2.2x slower. Current chunking is
//    the balance-vs-writeback optimum.
//  - R9 cg::grid.sync()+plain stores: WRONG (absmax 0.55; XCD-L2 non-coherent).
//  - R10 hand-rolled agent-scope spin barrier: correct but ~125us (spinning
//    acquire loads wreck caches). Grid-wide sync inside one kernel is poisoned;
//    the kernel-launch boundary IS the cheap grid barrier (~2us).

typedef __attribute__((ext_vector_type(8))) short bf16x8;
typedef __attribute__((ext_vector_type(4))) float f32x4;

__device__ __forceinline__ ushort f2bf(float f) {
  uint32_t u = __float_as_uint(f);
  u += 0x7fffu + ((u >> 16) & 1u);
  return (ushort)(u >> 16);
}

__device__ __forceinline__ uint cvt_pk(float lo, float hi) {
  uint r;
  asm volatile("v_cvt_pk_bf16_f32 %0, %1, %2" : "=v"(r) : "v"(lo), "v"(hi));
  return r;
}

// ---- merged preprocessing: repacks + pad_cvt + bn_fold + P1 border zero ----

template <int KK>
__device__ __forceinline__ void repack_dev(const float* __restrict__ src,
                                           ushort* __restrict__ dst, int M, int co,
                                           char* smraw) {
  if constexpr (KK == 1) {  // identity layout: plain f32->bf16 cast, no LDS
    int tid = threadIdx.x;
    dst[(size_t)co * 256 + tid] = f2bf(src[(size_t)co * 256 + tid]);
    return;
  } else {
    ushort(*t)[KK + 1] = (ushort(*)[KK + 1])smraw;
    int tid = threadIdx.x;
    for (int idx = tid; idx < 256 * KK; idx += 256) {
      int ci = idx / KK, k = idx - ci * KK;
      t[ci][k] = f2bf(src[(size_t)co * 256 * KK + idx]);
    }
    __syncthreads();
    for (int idx = tid; idx < 256 * KK; idx += 256) {
      int k = idx >> 8, ci = idx & 255;
      dst[((size_t)k * M + co) * 256 + ci] = t[ci][k];
    }
  }
}

__device__ __forceinline__ void pad_dev(const float* __restrict__ src,
                                        ushort* __restrict__ dst, int y, int b,
                                        char* smraw) {
  ushort(*t)[258] = (ushort(*)[258])smraw;
  int tid = threadIdx.x;
  for (int u = 0; u < 32; ++u) {
    int idx = u * 256 + tid;
    int c = idx >> 5, p = idx & 31;
    t[p][c] = f2bf(src[(((size_t)b * 256 + c) << 10) + (y << 5) + p]);
  }
  __syncthreads();
  for (int u = 0; u < 32; ++u) {
    int idx = u * 256 + tid;
    int p = idx >> 8, c = idx & 255;
    dst[(((size_t)b * 38 + y + 3) * 38 + p + 3) * 256 + c] = t[p][c];
  }
}

__global__ __launch_bounds__(256) void prep_all(
    const float* __restrict__ qkv_w, const float* __restrict__ out_w,
    const float* __restrict__ cw1, const float* __restrict__ cw3,
    const float* __restrict__ cw5, const float* __restrict__ cw7,
    ushort* __restrict__ Wq, ushort* __restrict__ Wo, ushort* __restrict__ Wc,
    const float* __restrict__ x, ushort* __restrict__ P1,
    const float* __restrict__ cb, const float* __restrict__ g,
    const float* __restrict__ be, const float* __restrict__ mn,
    const float* __restrict__ v, float* __restrict__ binv, float* __restrict__ bb2) {
  __shared__ __align__(16) char sm[25600];
  int gx = blockIdx.x;
  if (gx < 768) repack_dev<1>(qkv_w, Wq, 768, gx, sm);
  else if (gx < 1024) repack_dev<1>(out_w, Wo, 256, gx - 768, sm);
  else if (gx < 1280) repack_dev<1>(cw1, Wc, 256, gx - 1024, sm);
  else if (gx < 1536) repack_dev<9>(cw3, Wc + 65536, 256, gx - 1280, sm);
  else if (gx < 1792) repack_dev<25>(cw5, Wc + 655360, 256, gx - 1536, sm);
  else if (gx < 2048) repack_dev<49>(cw7, Wc + 2293760, 256, gx - 1792, sm);
  else if (gx < 2304) pad_dev(x, P1, (gx - 2048) & 31, (gx - 2048) >> 5, sm);
  else if (gx == 2304) {
    int tid = threadIdx.x;
#pragma unroll
    for (int u = 0; u < 4; ++u) {
      int i = u * 256 + tid;
      float inv = g[i] * rsqrtf(v[i] + 1e-5f);
      binv[i] = inv;
      bb2[i] = be[i] + (cb[i] - mn[i]) * inv;
    }
  } else {  // gx in [2305, 2369): zero P1 padded border (420 px x 256 ch per b)
    int z = gx - 2305;     // 0..63
    int b = z >> 3;        // 0..7
    int part = z & 7;      // 8 parts x 1680 uint4
    uint4* b4 = (uint4*)(P1 + (size_t)b * 369664);
    uint4 z4; z4.x = z4.y = z4.z = z4.w = 0u;
    for (int q = 0; q < 7; ++q) {
      int idx = q * 256 + threadIdx.x;
      if (idx < 1680) {
        int uidx = part * 1680 + idx;
        int p = uidx >> 5, ch = uidx & 31;
        int y, xx;
        if (p < 114) { y = p / 38; xx = p - y * 38; }
        else if (p < 306) {
          int r = p - 114; int ry = r / 6; int xi = r - ry * 6;
          y = 3 + ry; xx = xi < 3 ? xi : xi + 32;
        } else {
          int r = p - 306; int ry = r / 38; y = 35 + ry; xx = r - ry * 38;
        }
        b4[(y * 38 + xx) * 32 + ch] = z4;
      }
    }
  }
}

// ---- core: implicit-im2col MFMA conv/GEMM.
// MODE 0: qkv split -> QT/KT/VT bf16; MODE 1: padded bf16 out;
// MODE 2: raw f32 out (plain store or atomic accumulate for K-split chunks)
// Per-tap sync: {issue A-prefetch; vmcnt(2); barrier; ds_read+MFMA; raw barrier}.
template <int MODE>
__device__ __forceinline__ void conv_core(
    const ushort* __restrict__ W, const ushort* __restrict__ X,
    float* __restrict__ outF, ushort* __restrict__ outU,
    int M, int KS, int b, int co0, int pxt, int cs0, int cs1, bool accum,
    char* smem) {
  const int R = KS >> 1;
  const int NT = KS * KS;
  const int NR = 4 + 2 * R;
  const int NPIX = NR * 38;
  char* Bs = smem;
  char* As = smem + 24320;
  const int tid = threadIdx.x;
  const int w = tid >> 6, l = tid & 63, lr = l & 15, sg = l >> 4;
  const int y0 = pxt * 4;
  const ushort* Xb = X + ((size_t)b * 38 + (y0 + 3 - R)) * 38 * 256;

  f32x4 acc[4][4] = {};

  auto stageA = [&](int t, int ci0, int bufsel) {
    const ushort* Wt = W + ((size_t)t * M + co0) * 256 + ci0;
    char* dbase = As + (bufsel << 13) + (w << 11);
#pragma unroll
    for (int u = 0; u < 2; ++u) {
      int idx16 = (w * 2 + u) * 64 + l;
      int co = idx16 >> 2, s = idx16 & 3;
      const ushort* src = Wt + (size_t)co * 256 + ((s ^ ((co >> 1) & 3)) << 3);
      __builtin_amdgcn_global_load_lds(
          (const __attribute__((address_space(1))) void*)src,
          (__attribute__((address_space(3))) void*)(dbase + (u << 10)), 16, 0, 0);
    }
  };

  int g = 0;
  stageA(0, cs0 << 5, 0);
  const int u_stg = (NPIX * 4 + 255) >> 8;
  for (int cs = cs0; cs < cs1; ++cs) {
    int ci0 = cs << 5;
    for (int u = 0; u < u_stg; ++u) {
      int idx = (u << 8) + tid;
      if (idx < NPIX * 4) {
        int pix = idx >> 2, s = idx & 3;
        int pr = pix / 38, pc = pix - pr * 38;
        const ushort* srcp = Xb + ((size_t)(pr * 38 + pc)) * 256 + ci0 +
                             ((s ^ ((pc >> 1) & 3)) << 3);
        __builtin_amdgcn_global_load_lds(
            (const __attribute__((address_space(1))) void*)srcp,
            (__attribute__((address_space(3))) void*)(Bs + (u << 12) + (w << 10)),
            16, 0, 0);
      }
    }
    __syncthreads();  // full drain: B tile + pending A prefetch must land
    int dy = 0, dx = 0;
    for (int t = 0; t < NT; ++t) {
      bool staged = true;
      if (t + 1 < NT) stageA(t + 1, ci0, (g + 1) & 1);
      else if (cs + 1 < cs1) stageA(0, ci0 + 32, (g + 1) & 1);
      else staged = false;
      if (staged)
        asm volatile("s_waitcnt vmcnt(2)\n\ts_barrier" ::: "memory");
      else
        asm volatile("s_waitcnt vmcnt(0)\n\ts_barrier" ::: "memory");

      bf16x8 af[4], bfr[4];
      char* Ab = As + ((g & 1) << 13);
#pragma unroll
      for (int fa = 0; fa < 4; ++fa) {
        int co = (w & 1) * 64 + fa * 16 + lr;
        af[fa] = *(const bf16x8*)(Ab + (co << 6) + ((sg ^ ((co >> 1) & 3)) << 4));
      }
      int rowbase = (w >> 1) * 2 + dy;
      int cbase = dx + 3 - R + lr;
#pragma unroll
      for (int fp = 0; fp < 4; ++fp) {
        int lrow = rowbase + (fp >> 1);
        int pc = cbase + ((fp & 1) << 4);
        bfr[fp] = *(const bf16x8*)(Bs + ((lrow * 38 + pc) << 6) +
                                   ((sg ^ ((pc >> 1) & 3)) << 4));
      }
      __builtin_amdgcn_s_setprio(1);
#pragma unroll
      for (int fa = 0; fa < 4; ++fa)
#pragma unroll
        for (int fp = 0; fp < 4; ++fp)
          acc[fa][fp] = __builtin_amdgcn_mfma_f32_16x16x32_bf16(
              af[fa], bfr[fp], acc[fa][fp], 0, 0, 0);
      __builtin_amdgcn_s_setprio(0);
      ++g;
      if (++dx == KS) { dx = 0; ++dy; }
      asm volatile("s_barrier" ::: "memory");
    }
  }
  // epilogue
  int coB = co0 + (w & 1) * 64;
  int pxB = pxt * 128 + (w >> 1) * 64;
#pragma unroll
  for (int fa = 0; fa < 4; ++fa) {
#pragma unroll
    for (int fp = 0; fp < 4; ++fp) {
      int px = pxB + (fp >> 1) * 32 + (fp & 1) * 16 + lr;
      int cobase = coB + fa * 16 + 4 * sg;
      f32x4 v4 = acc[fa][fp];
      if (MODE == 2) {
#pragma unroll
        for (int r = 0; r < 4; ++r) {
          int co = cobase + r;
          float* dst = &outF[((size_t)b * M + co) * 1024 + px];
          if (accum) unsafeAtomicAdd(dst, v4[r]);
          else *dst = v4[r];
        }
      } else if (MODE == 1) {
        int y = px >> 5, x = px & 31;
        ushort* dst = outU + ((size_t)(b * 38 + y + 3) * 38 + x + 3) * 256 + cobase;
        *(uint*)dst = cvt_pk(v4[0], v4[1]);
        *(uint*)(dst + 2) = cvt_pk(v4[2], v4[3]);
      } else {  // MODE 0: split into QT / KT / VT
        if (coB < 256) {
          int h = cobase >> 5, d = cobase & 31;
          ushort* dst = outU + ((size_t)(b * 8 + h) * 1024 + px) * 32 + d;
          const float sc = 0.17677669529663687f;
          *(uint*)dst = cvt_pk(v4[0] * sc, v4[1] * sc);
          *(uint*)(dst + 2) = cvt_pk(v4[2] * sc, v4[3] * sc);
        } else if (coB < 512) {
          int c2 = cobase - 256;
          int h = c2 >> 5, d = c2 & 31;
          ushort* dst = outU + 2097152 + ((size_t)(b * 8 + h) * 1024 + px) * 32 + d;
          *(uint*)dst = cvt_pk(v4[0], v4[1]);
          *(uint*)(dst + 2) = cvt_pk(v4[2], v4[3]);
        } else {
          int c2 = cobase - 512;
#pragma unroll
          for (int r = 0; r < 4; ++r)
            outU[4194304 + ((size_t)(b * 256 + c2 + r)) * 1024 + px] = f2bf(v4[r]);
        }
      }
    }
  }
}

__global__ __launch_bounds__(256, 2) void gemm_qkv(const ushort* __restrict__ W,
                                                   const ushort* __restrict__ X,
                                                   ushort* __restrict__ U) {
  __shared__ __align__(16) char smem[40704];
  int cot = blockIdx.x >> 3, pxt = blockIdx.x & 7, b = blockIdx.y;
  conv_core<0>(W, X, nullptr, U, 768, 1, b, cot * 128, pxt, 0, 8, false, smem);
}

// oproj + feats-plane zeroing tail (replaces the 25 MB memset dispatch).
// Planes 1-3 alias KT/VT; legal because oproj runs after flash_attn.
__global__ __launch_bounds__(256, 2) void gemm_oproj(const ushort* __restrict__ W,
                                                     const ushort* __restrict__ X,
                                                     ushort* __restrict__ U,
                                                     float* __restrict__ fz) {
  __shared__ __align__(16) char smem[40704];
  int cot = blockIdx.x >> 3, pxt = blockIdx.x & 7, b = blockIdx.y;
  conv_core<1>(W, X, nullptr, U, 256, 1, b, cot * 128, pxt, 0, 8, false, smem);
  // zero 25165824 B across 128 blocks: 196608 B/block = 12288 float4
  int blk = blockIdx.y * 16 + blockIdx.x;
  float4* dst = (float4*)fz + (size_t)blk * 12288;
  float4 z4 = {0.f, 0.f, 0.f, 0.f};
#pragma unroll
  for (int q = 0; q < 48; ++q) dst[q * 256 + threadIdx.x] = z4;
}

// 1024 blocks, all co-resident (4 blocks/CU @ 40.75KB LDS, 16 waves/CU).
// K-chunked for balance (tap-units): k7 -> 4 chunks of 2 cs (98, 512 blocks),
// k5 -> 2 chunks of 4 cs (100, 256), k3 -> 2 chunks of 4 cs (36, 256);
// k3-chunk0 blocks additionally run the tiny k1 (8). Per-CU load: 340/332 taps.
__global__ __launch_bounds__(256, 4) void conv_fused(const ushort* __restrict__ Wc,
                                                     const ushort* __restrict__ X,
                                                     float* __restrict__ feats) {
  __shared__ __align__(16) char smem[40704];
  int gx = blockIdx.x;
  int sub = gx & 127;
  int pxt = sub & 7, cot = (sub >> 3) & 1, b = sub >> 4;
  int br, cs0, cs1;
  if (gx < 512) {
    br = 3; int ch = gx >> 7; cs0 = ch * 2; cs1 = cs0 + 2;
  } else if (gx < 768) {
    br = 2; int ch = (gx >> 7) & 1; cs0 = ch * 4; cs1 = cs0 + 4;
  } else {
    br = 1; int ch = (gx >> 7) & 1; cs0 = ch * 4; cs1 = cs0 + 4;
  }
  const int ksarr[4] = {1, 3, 5, 7};
  const int wofs[4] = {0, 65536, 655360, 2293760};
  conv_core<2>(Wc + wofs[br], X, feats + (size_t)br * 2097152, nullptr, 256,
               ksarr[br], b, cot * 128, pxt, cs0, cs1, true, smem);
  if (gx >= 768 && gx < 896) {  // k3-chunk0 blocks also do k1 (plain store)
    __syncthreads();
    conv_core<2>(Wc, X, feats, nullptr, 256, 1, b, cot * 128, pxt, 0, 8, false,
                 smem);
  }
}

// ---- flash attention: QT/KT [bh][1024][32] bf16, VT [b*256+c][1024] bf16.
// Grid (8 qtiles, 64 bh). 4 waves x 32 queries. KV tiles of 64.
// K/V register-direct (L2-resident), 2-deep dbuf, barrier-free.
__global__ __launch_bounds__(256, 2) void flash_attn(const ushort* __restrict__ QKV,
                                                     ushort* __restrict__ P2out) {
  __shared__ __align__(16) char smem[16384];
  const int tid = threadIdx.x, w = tid >> 6, l = tid & 63, lr = l & 15, sg = l >> 4;
  char* Ps = smem + (w << 12);  // per-wave [32 i][8 slots 16B] swizzled
  int bh = blockIdx.y, b = bh >> 3, h = bh & 7;
  const ushort* QT = QKV + (size_t)bh * 32768;
  const ushort* KT = QKV + 2097152 + (size_t)bh * 32768;
  const ushort* VT = QKV + 4194304 + (size_t)(b * 256 + h * 32) * 1024;
  int ibase = blockIdx.x * 128 + w * 32;

  bf16x8 qf[2];
#pragma unroll
  for (int i16 = 0; i16 < 2; ++i16)
    qf[i16] = *(const bf16x8*)(QT + ((size_t)(ibase + i16 * 16 + lr)) * 32 + sg * 8);

  f32x4 oacc[4] = {};  // [d16*2 + i16]
  float mrow[2] = {-3e30f, -3e30f};
  float lrow[2] = {0.f, 0.f};

  const ushort* Krow = KT + (size_t)lr * 32 + sg * 8;
  const ushort* Vrow = VT + (size_t)lr * 1024 + sg * 8;

  bf16x8 k0[4], v0[4], k1[4], v1[4];
  auto LK = [&](int jb, bf16x8* kf) {
#pragma unroll
    for (int jt = 0; jt < 4; ++jt)
      kf[jt] = *(const bf16x8*)(Krow + ((size_t)jb + jt * 16) * 32);
  };
  auto LV = [&](int jb, bf16x8* vf) {
#pragma unroll
    for (int d16 = 0; d16 < 2; ++d16)
#pragma unroll
      for (int h2 = 0; h2 < 2; ++h2)
        vf[d16 * 2 + h2] =
            *(const bf16x8*)(Vrow + (size_t)d16 * 16384 + jb + h2 * 32);
  };

  auto body = [&](int jb, bf16x8* kc, bf16x8* vc, bf16x8* kn, bf16x8* vn) {
    if (jb + 64 < 1024) { LK(jb + 64, kn); LV(jb + 64, vn); }  // prefetch next
    f32x4 sac[2][4] = {};
#pragma unroll
    for (int i16 = 0; i16 < 2; ++i16)
#pragma unroll
      for (int jt = 0; jt < 4; ++jt)
        sac[i16][jt] = __builtin_amdgcn_mfma_f32_16x16x32_bf16(
            kc[jt], qf[i16], sac[i16][jt], 0, 0, 0);

#pragma unroll
    for (int i16 = 0; i16 < 2; ++i16) {
      float tmax = sac[i16][0][0];
#pragma unroll
      for (int jt = 0; jt < 4; ++jt)
#pragma unroll
        for (int r = 0; r < 4; ++r) tmax = fmaxf(tmax, sac[i16][jt][r]);
      tmax = fmaxf(tmax, __shfl_xor(tmax, 16));
      tmax = fmaxf(tmax, __shfl_xor(tmax, 32));
      float mnew = fmaxf(mrow[i16], tmax);
      float fac = __expf(mrow[i16] - mnew);
      mrow[i16] = mnew;
      float psum = 0.f;
      int i = i16 * 16 + lr;
      char* prow = Ps + i * 128;
#pragma unroll
      for (int jt = 0; jt < 4; ++jt) {
        float p0 = __expf(sac[i16][jt][0] - mnew);
        float p1 = __expf(sac[i16][jt][1] - mnew);
        float p2 = __expf(sac[i16][jt][2] - mnew);
        float p3 = __expf(sac[i16][jt][3] - mnew);
        psum += (p0 + p1) + (p2 + p3);
        int j0 = jt * 16 + sg * 4;
        uint* dst = (uint*)(prow + (((j0 >> 3) ^ (i & 7)) << 4) + ((j0 & 7) << 1));
        dst[0] = cvt_pk(p0, p1);
        dst[1] = cvt_pk(p2, p3);
      }
      lrow[i16] = lrow[i16] * fac + psum;
#pragma unroll
      for (int d16 = 0; d16 < 2; ++d16)
#pragma unroll
        for (int r = 0; r < 4; ++r) oacc[d16 * 2 + i16][r] *= fac;
    }
    asm volatile("s_waitcnt lgkmcnt(0)" ::: "memory");

#pragma unroll
    for (int h2 = 0; h2 < 2; ++h2) {
      bf16x8 pf[2];
#pragma unroll
      for (int i16 = 0; i16 < 2; ++i16) {
        int i = i16 * 16 + lr;
        pf[i16] = *(const bf16x8*)(Ps + i * 128 + ((((h2 << 2) + sg) ^ (i & 7)) << 4));
      }
#pragma unroll
      for (int d16 = 0; d16 < 2; ++d16)
#pragma unroll
        for (int i16 = 0; i16 < 2; ++i16)
          oacc[d16 * 2 + i16] = __builtin_amdgcn_mfma_f32_16x16x32_bf16(
              vc[d16 * 2 + h2], pf[i16], oacc[d16 * 2 + i16], 0, 0, 0);
    }
  };

  LK(0, k0);
  LV(0, v0);
#pragma unroll 1
  for (int jb = 0; jb < 1024; jb += 128) {
    body(jb, k0, v0, k1, v1);
    body(jb + 64, k1, v1, k0, v0);
  }

  float linv[2];
#pragma unroll
  for (int i16 = 0; i16 < 2; ++i16) {
    float lt = lrow[i16];
    lt += __shfl_xor(lt, 16);
    lt += __shfl_xor(lt, 32);
    linv[i16] = 1.0f / lt;
  }
#pragma unroll
  for (int i16 = 0; i16 < 2; ++i16) {
    int i = ibase + i16 * 16 + lr;
    int y = i >> 5, x = i & 31;
    ushort* dst0 = P2out + ((size_t)(b * 38 + y + 3) * 38 + x + 3) * 256 + h * 32 + sg * 4;
#pragma unroll
    for (int d16 = 0; d16 < 2; ++d16) {
      f32x4 v = oacc[d16 * 2 + i16];
      ushort* dst = dst0 + d16 * 16;
      *(uint*)dst = cvt_pk(v[0] * linv[i16], v[1] * linv[i16]);
      *(uint*)(dst + 2) = cvt_pk(v[2] * linv[i16], v[3] * linv[i16]);
    }
  }
}

// ---- S = mean over pixels of sum_k relu(BN(feats_raw))
__global__ __launch_bounds__(256) void reduce_s(const float* __restrict__ feats,
                                                const float* __restrict__ binv,
                                                const float* __restrict__ bb2,
                                                float* __restrict__ S) {
  int bc = blockIdx.x;
  int c = bc & 255;
  const float4* p4 = (const float4*)feats + (size_t)bc * 256;
  float s = 0;
#pragma unroll
  for (int k = 0; k < 4; ++k) {
    float bi = binv[k * 256 + c], bo = bb2[k * 256 + c];
    float4 v = p4[(size_t)k * 524288 + threadIdx.x];
    s += fmaxf(fmaf(v.x, bi, bo), 0.f) + fmaxf(fmaf(v.y, bi, bo), 0.f) +
         fmaxf(fmaf(v.z, bi, bo), 0.f) + fmaxf(fmaf(v.w, bi, bo), 0.f);
  }
  __shared__ float red[256];
  red[threadIdx.x] = s;
  __syncthreads();
  for (int off = 128; off > 0; off >>= 1) {
    if (threadIdx.x < off) red[threadIdx.x] += red[threadIdx.x + off];
    __syncthreads();
  }
  if (threadIdx.x == 0) S[bc] = red[0] * (1.0f / 1024.0f);
}

// ---- combine + inline fc/softmax (replaces fc_attn_k + combine_k).
// 2048 blocks; block blk owns (b = blk>>8, c = blk&255), 256 float4 pixels.
// Z recomputed per block from S via parallel partial sums (tid -> (d, c-chunk):
// 32 MACs/thread + LDS reduce). S coherent via the reduce_s kernel boundary.
__global__ __launch_bounds__(256) void combine_fc(
    const float* __restrict__ feats, const float* __restrict__ S,
    const float* __restrict__ binv, const float* __restrict__ bb2,
    const float* __restrict__ fc_w, const float* __restrict__ fc_b,
    const float* __restrict__ fcs_w, const float* __restrict__ fcs_b,
    float* __restrict__ out) {
  __shared__ float Ss[256];
  __shared__ float part[256];
  __shared__ float Zs[32];
  const int tid = threadIdx.x;
  const int blk = blockIdx.x;
  const int b = blk >> 8, c = blk & 255;

  Ss[tid] = S[b * 256 + tid];
  __syncthreads();
  {  // Z[d] = fc_b[d] + sum_c S[c]*fc_w[d*256+c], parallel over 256 threads
    int d = tid >> 3, ch = tid & 7;
    const float* wp = &fc_w[d * 256 + ch * 32];
    float p = 0.f;
#pragma unroll
    for (int j = 0; j < 32; ++j) p += Ss[ch * 32 + j] * wp[j];
    part[tid] = p;
  }
  __syncthreads();
  if (tid < 32) {
    float z = fc_b[tid];
#pragma unroll
    for (int ch = 0; ch < 8; ++ch) z += part[tid * 8 + ch];
    Zs[tid] = z;
  }
  __syncthreads();

  // logits + softmax (block-uniform in c; computed per thread, cheap)
  float lg[4];
#pragma unroll
  for (int k = 0; k < 4; ++k) {
    float v = fcs_b[k * 256 + c];
    const float* wp = &fcs_w[((size_t)k * 256 + c) * 32];
#pragma unroll
    for (int d = 0; d < 32; ++d) v += wp[d] * Zs[d];
    lg[k] = v;
  }
  float m = fmaxf(fmaxf(lg[0], lg[1]), fmaxf(lg[2], lg[3]));
  float e0 = __expf(lg[0] - m), e1 = __expf(lg[1] - m);
  float e2 = __expf(lg[2] - m), e3 = __expf(lg[3] - m);
  float inv = 1.0f / (e0 + e1 + e2 + e3);
  float aw[4] = {e0 * inv, e1 * inv, e2 * inv, e3 * inv};

  size_t i4 = (size_t)blk * 256 + tid;
  float4 s = {0.f, 0.f, 0.f, 0.f};
#pragma unroll
  for (int k = 0; k < 4; ++k) {
    float bi = binv[k * 256 + c], bo = bb2[k * 256 + c];
    float4 v = ((const float4*)feats)[(size_t)k * 524288 + i4];
    s.x += aw[k] * fmaxf(fmaf(v.x, bi, bo), 0.f);
    s.y += aw[k] * fmaxf(fmaf(v.y, bi, bo), 0.f);
    s.z += aw[k] * fmaxf(fmaf(v.z, bi, bo), 0.f);
    s.w += aw[k] * fmaxf(fmaf(v.w, bi, bo), 0.f);
  }
  ((float4*)out)[i4] = s;
}

extern "C" void kernel_launch(void* const* d_in, const int* in_sizes, int n_in,
                              void* d_out, int out_size, void* d_ws, size_t ws_size,
                              hipStream_t stream) {
  (void)in_sizes; (void)n_in; (void)out_size; (void)ws_size;
  const float* x      = (const float*)d_in[0];
  const float* qkv_w  = (const float*)d_in[1];
  const float* out_w  = (const float*)d_in[2];
  const float* cw1    = (const float*)d_in[3];
  const float* cw3    = (const float*)d_in[4];
  const float* cw5    = (const float*)d_in[5];
  const float* cw7    = (const float*)d_in[6];
  const float* conv_b = (const float*)d_in[7];
  const float* bn_g   = (const float*)d_in[8];
  const float* bn_b   = (const float*)d_in[9];
  const float* bn_m   = (const float*)d_in[10];
  const float* bn_v   = (const float*)d_in[11];
  const float* fc_w   = (const float*)d_in[12];
  const float* fc_b   = (const float*)d_in[13];
  const float* fcs_w  = (const float*)d_in[14];
  const float* fcs_b  = (const float*)d_in[15];

  char*  wsb   = (char*)d_ws;
  float* wsf   = (float*)d_ws;
  ushort* QKVb = (ushort*)d_ws;             // QT | KT(+2097152) | VT(+4194304)
  float* feats = wsf;                       // overlaps QKV buffers (dead by then)
  float* S     = wsf + 10485760;
  ushort* P1   = (ushort*)(wsb + 41984000);
  ushort* P2   = (ushort*)(wsb + 47898624);
  ushort* Wq   = (ushort*)(wsb + 53813248);
  ushort* Wo   = (ushort*)(wsb + 54206464);
  ushort* Wc   = (ushort*)(wsb + 54337536);
  float* binv  = (float*)(wsb + 65347584);
  float* bb2   = (float*)(wsb + 65351680);
  float* out   = (float*)d_out;

  prep_all<<<2369, 256, 0, stream>>>(qkv_w, out_w, cw1, cw3, cw5, cw7, Wq, Wo, Wc,
                                     x, P1, conv_b, bn_g, bn_b, bn_m, bn_v,
                                     binv, bb2);

  gemm_qkv<<<dim3(48, 8), 256, 0, stream>>>(Wq, P1, QKVb);
  flash_attn<<<dim3(8, 64), 256, 0, stream>>>(QKVb, P2);
  // gemm_oproj's tail zeroes feats planes 1-3 (alias KT/VT; flash is done).
  gemm_oproj<<<dim3(16, 8), 256, 0, stream>>>(Wo, P2, P1, (float*)(wsb + 8388608));
  conv_fused<<<dim3(1024), 256, 0, stream>>>(Wc, P1, feats);

  reduce_s<<<2048, 256, 0, stream>>>(feats, binv, bb2, S);
  combine_fc<<<2048, 256, 0, stream>>>(feats, S, binv, bb2, fc_w, fc_b, fcs_w,
                                       fcs_b, out);
}